// Round 5
// baseline (81.860 us; speedup 1.0000x reference)
//
#include <hip/hip_runtime.h>
#include <hip/hip_bf16.h>

// 2x2-patch softmax on a [B=16, C=64, H=256, W=256] fp32 tensor.
// Patch = rows (2h,2h+1) x cols (2w,2w+1). Softmax over the 4 values.
//
// Memory-bound streaming: 256 MiB read (L3 absorbs ~half across replays)
// + 256 MiB write (nt stores, compulsory HBM).
// Round 5: ILP=4 — four independent float4-pairs per thread, all 8 loads
// issued before any compute. Regular loads (L3-friendly), nt stores.

#define W 256
#define N4_TOTAL (16 * 64 * 128 * 64)  // (B*C*H/2) rowpairs * (W/4) float4/row
#define QTR (N4_TOTAL / 4)

typedef float v4f __attribute__((ext_vector_type(4)));

__device__ __forceinline__ void softmax_pair(v4f t, v4f b, v4f& ot, v4f& ob) {
    // Patch A: {t.x, t.y, b.x, b.y}
    float mA = fmaxf(fmaxf(t.x, t.y), fmaxf(b.x, b.y));
    float eA0 = __expf(t.x - mA);
    float eA1 = __expf(t.y - mA);
    float eA2 = __expf(b.x - mA);
    float eA3 = __expf(b.y - mA);
    float invA = 1.0f / (eA0 + eA1 + eA2 + eA3);
    // Patch B: {t.z, t.w, b.z, b.w}
    float mB = fmaxf(fmaxf(t.z, t.w), fmaxf(b.z, b.w));
    float eB0 = __expf(t.z - mB);
    float eB1 = __expf(t.w - mB);
    float eB2 = __expf(b.z - mB);
    float eB3 = __expf(b.w - mB);
    float invB = 1.0f / (eB0 + eB1 + eB2 + eB3);
    ot = (v4f){eA0 * invA, eA1 * invA, eB0 * invB, eB1 * invB};
    ob = (v4f){eA2 * invA, eA3 * invA, eB2 * invB, eB3 * invB};
}

__global__ __launch_bounds__(256) void patch_softmax2x2(
    const float* __restrict__ x, float* __restrict__ y) {
    int i = blockIdx.x * blockDim.x + threadIdx.x;  // [0, QTR)

    long base[4];
#pragma unroll
    for (int k = 0; k < 4; ++k) {
        int idx = i + k * QTR;
        int r = idx >> 6;
        int q = idx & 63;
        base[k] = (long)r * (2 * W) + q * 4;
    }

    // Issue all 8 loads before any compute (max loads in flight).
    v4f t0 = *reinterpret_cast<const v4f*>(x + base[0]);
    v4f b0 = *reinterpret_cast<const v4f*>(x + base[0] + W);
    v4f t1 = *reinterpret_cast<const v4f*>(x + base[1]);
    v4f b1 = *reinterpret_cast<const v4f*>(x + base[1] + W);
    v4f t2 = *reinterpret_cast<const v4f*>(x + base[2]);
    v4f b2 = *reinterpret_cast<const v4f*>(x + base[2] + W);
    v4f t3 = *reinterpret_cast<const v4f*>(x + base[3]);
    v4f b3 = *reinterpret_cast<const v4f*>(x + base[3] + W);

    v4f ot, ob;
    softmax_pair(t0, b0, ot, ob);
    __builtin_nontemporal_store(ot, reinterpret_cast<v4f*>(y + base[0]));
    __builtin_nontemporal_store(ob, reinterpret_cast<v4f*>(y + base[0] + W));
    softmax_pair(t1, b1, ot, ob);
    __builtin_nontemporal_store(ot, reinterpret_cast<v4f*>(y + base[1]));
    __builtin_nontemporal_store(ob, reinterpret_cast<v4f*>(y + base[1] + W));
    softmax_pair(t2, b2, ot, ob);
    __builtin_nontemporal_store(ot, reinterpret_cast<v4f*>(y + base[2]));
    __builtin_nontemporal_store(ob, reinterpret_cast<v4f*>(y + base[2] + W));
    softmax_pair(t3, b3, ot, ob);
    __builtin_nontemporal_store(ot, reinterpret_cast<v4f*>(y + base[3]));
    __builtin_nontemporal_store(ob, reinterpret_cast<v4f*>(y + base[3] + W));
}

extern "C" void kernel_launch(void* const* d_in, const int* in_sizes, int n_in,
                              void* d_out, int out_size, void* d_ws, size_t ws_size,
                              hipStream_t stream) {
    const float* x = (const float*)d_in[0];
    float* y = (float*)d_out;
    patch_softmax2x2<<<QTR / 256, 256, 0, stream>>>(x, y);  // 8192 blocks
}

// Round 6
// 80.105 us; speedup vs baseline: 1.0219x; 1.0219x over previous
//
#include <hip/hip_runtime.h>
#include <hip/hip_bf16.h>

// 2x2-patch softmax on a [B=16, C=64, H=256, W=256] fp32 tensor.
// Patch = rows (2h,2h+1) x cols (2w,2w+1). Softmax over the 4 values.
//
// FINAL (measured-best, round 4): ILP=2 — two independent float4-pairs per
// thread, all 4 loads issued before compute. Regular loads (input = exactly
// 256 MiB = L3 size; L3 retains ~half across replays -> FETCH ~134 MB),
// nontemporal stores (write-once output, don't evict the input from L3).
// 80.2 us = 536.9 MB logical / 80.2 us = 6.7 TB/s effective (above the
// 6.29 TB/s HBM copy ceiling thanks to L3 hits). ILP=4 regressed (81.9 us);
// nt loads regressed (99.2 us, forces HBM re-fetch of the L3-resident half).

#define W 256
#define N4_TOTAL (16 * 64 * 128 * 64)  // (B*C*H/2) rowpairs * (W/4) float4/row
#define HALF (N4_TOTAL / 2)

typedef float v4f __attribute__((ext_vector_type(4)));

__device__ __forceinline__ void softmax_pair(v4f t, v4f b, v4f& ot, v4f& ob) {
    // Patch A: {t.x, t.y, b.x, b.y}
    float mA = fmaxf(fmaxf(t.x, t.y), fmaxf(b.x, b.y));
    float eA0 = __expf(t.x - mA);
    float eA1 = __expf(t.y - mA);
    float eA2 = __expf(b.x - mA);
    float eA3 = __expf(b.y - mA);
    float invA = 1.0f / (eA0 + eA1 + eA2 + eA3);
    // Patch B: {t.z, t.w, b.z, b.w}
    float mB = fmaxf(fmaxf(t.z, t.w), fmaxf(b.z, b.w));
    float eB0 = __expf(t.z - mB);
    float eB1 = __expf(t.w - mB);
    float eB2 = __expf(b.z - mB);
    float eB3 = __expf(b.w - mB);
    float invB = 1.0f / (eB0 + eB1 + eB2 + eB3);
    ot = (v4f){eA0 * invA, eA1 * invA, eB0 * invB, eB1 * invB};
    ob = (v4f){eA2 * invA, eA3 * invA, eB2 * invB, eB3 * invB};
}

__global__ __launch_bounds__(256) void patch_softmax2x2(
    const float* __restrict__ x, float* __restrict__ y) {
    int i = blockIdx.x * blockDim.x + threadIdx.x;  // [0, HALF)

    int r0 = i >> 6;
    int q0 = i & 63;
    long base0 = (long)r0 * (2 * W) + q0 * 4;

    int j = i + HALF;
    int r1 = j >> 6;
    int q1 = j & 63;
    long base1 = (long)r1 * (2 * W) + q1 * 4;

    // Issue all 4 loads before any compute (MLP).
    v4f t0 = *reinterpret_cast<const v4f*>(x + base0);
    v4f b0 = *reinterpret_cast<const v4f*>(x + base0 + W);
    v4f t1 = *reinterpret_cast<const v4f*>(x + base1);
    v4f b1 = *reinterpret_cast<const v4f*>(x + base1 + W);

    v4f ot0, ob0, ot1, ob1;
    softmax_pair(t0, b0, ot0, ob0);
    softmax_pair(t1, b1, ot1, ob1);

    __builtin_nontemporal_store(ot0, reinterpret_cast<v4f*>(y + base0));
    __builtin_nontemporal_store(ob0, reinterpret_cast<v4f*>(y + base0 + W));
    __builtin_nontemporal_store(ot1, reinterpret_cast<v4f*>(y + base1));
    __builtin_nontemporal_store(ob1, reinterpret_cast<v4f*>(y + base1 + W));
}

extern "C" void kernel_launch(void* const* d_in, const int* in_sizes, int n_in,
                              void* d_out, int out_size, void* d_ws, size_t ws_size,
                              hipStream_t stream) {
    const float* x = (const float*)d_in[0];
    float* y = (float*)d_out;
    patch_softmax2x2<<<HALF / 256, 256, 0, stream>>>(x, y);  // 16384 blocks
}